// Round 3
// baseline (513.689 us; speedup 1.0000x reference)
//
#include <hip/hip_runtime.h>
#include <hip/hip_bf16.h>

#define BATCH   256
#define NLAYERS 32
#define HID     1024
#define INTER   2816

typedef __attribute__((ext_vector_type(8))) short bf16x8;
typedef __attribute__((ext_vector_type(4))) float f32x4;
typedef __attribute__((ext_vector_type(4))) int   i32x4;

__device__ __forceinline__ ushort f2bf(float f) {
  __hip_bfloat16 b = __float2bfloat16(f);   // RNE; compiler pairs into v_cvt_pk_bf16_f32
  return *reinterpret_cast<ushort*>(&b);
}

__device__ __forceinline__ bf16x8 cvt8(f32x4 a, f32x4 b) {
  bf16x8 o;
  o[0] = (short)f2bf(a[0]); o[1] = (short)f2bf(a[1]);
  o[2] = (short)f2bf(a[2]); o[3] = (short)f2bf(a[3]);
  o[4] = (short)f2bf(b[0]); o[5] = (short)f2bf(b[1]);
  o[6] = (short)f2bf(b[2]); o[7] = (short)f2bf(b[3]);
  return o;
}

// ---------------------------------------------------------------------------
// Kernel 1: act[layer][b][i] = silu(X Wg^T) * (X Wu^T), bf16 -> ws.
// BM=256 (weights from HBM exactly once), BN=32, BK=64.
// 512 threads = 8 waves decomposed 8Mx1N: wave w owns batch rows w*32..w*32+31
// exclusively -> A-fragments are loaded DIRECTLY from global (X is 1MB/layer,
// L2-resident; no LDS, no barrier dependency, no staging VGPRs for X).
// Only Wg/Wu tiles (32x64 fp32 = 8KB -> 8KB bf16 LDS... 4KB each) go through
// LDS, double-buffered, with the R1-verified zero-conflict XOR swizzle
// (slot ^ (row&7) on 128B rows). One barrier per k-step; 2-deep weight
// register prefetch ordered so the compiler emits counted vmcnt (W(t+2)
// issued before W(t+1) regs are consumed).
// __launch_bounds__(512,4): VGPR<=128 -> 2 blocks (16 waves) per CU.
// ---------------------------------------------------------------------------
__global__ __launch_bounds__(512, 4) void k_gateup(
    const float* __restrict__ h, const float* __restrict__ Wg,
    const float* __restrict__ Wu, ushort* __restrict__ act) {
  const int bid   = blockIdx.x;
  const int layer = bid / (INTER / 32);   // 88 itiles per layer
  const int it    = bid % (INTER / 32);
  const int i0    = it * 32;
  const int tid   = threadIdx.x;
  const int lane  = tid & 63;
  const int wave  = tid >> 6;             // 0..7 -> M rows [wave*32, wave*32+32)
  const int m0    = wave * 32;

  // [buf][g=0/u=1][32 rows * 64 cols] bf16, XOR-swizzled 16B slots
  __shared__ ushort Wl[2][2][32 * 64];    // 16 KiB total

  f32x4 ag[2][2] = {}, au[2][2] = {};     // [m][n] accumulators

  // ---- weight staging geometry: threads 0-255 stage G, 256-511 stage U.
  // granule = 8 consecutive k-floats of one row (16B bf16 = one LDS slot).
  const int half = tid >> 8;              // 0=G, 1=U
  const int w    = tid & 255;
  const int wrow = w >> 3;                // 0..31
  const int wsl  = w & 7;                 // 0..7
  const int wldst = wrow * 64 + ((wsl ^ (wrow & 7)) << 3);
  const float* wsrc = (half ? Wu : Wg) +
      (size_t)layer * INTER * HID + (size_t)(i0 + wrow) * HID + wsl * 8;

  // ---- X direct-load pointers (per wave-exclusive rows)
  const int r16 = lane & 15;
  const int g4  = lane >> 4;              // 16B-slot sub-index 0..3
  const float* xp[2];
#pragma unroll
  for (int m = 0; m < 2; ++m)
    xp[m] = h + (size_t)(m0 + m * 16 + r16) * (NLAYERS * HID) +
            (size_t)layer * HID + g4 * 8;

  // ---- prologue: W(0), W(1) in regs; W(0) -> buf0
  f32x4 rw[2][2];
  rw[0][0] = *(const f32x4*)(wsrc);       rw[0][1] = *(const f32x4*)(wsrc + 4);
  rw[1][0] = *(const f32x4*)(wsrc + 64);  rw[1][1] = *(const f32x4*)(wsrc + 68);
  *(bf16x8*)&Wl[0][half][wldst] = cvt8(rw[0][0], rw[0][1]);
  __syncthreads();

  const int NK = HID / 64;                // 16 k-steps
  for (int t = 0; t < NK; ++t) {
    const int cur = t & 1;

    // (1) issue W(t+2) into the reg pair whose data is already in LDS
    if (t + 2 < NK) {
      rw[t & 1][0] = *(const f32x4*)(wsrc + (t + 2) * 64);
      rw[t & 1][1] = *(const f32x4*)(wsrc + (t + 2) * 64 + 4);
    }
    // (2) issue X fragment loads for tile t (L2 hits after first block/layer)
    f32x4 xr[2][2][2];
#pragma unroll
    for (int ks = 0; ks < 2; ++ks)
#pragma unroll
      for (int m = 0; m < 2; ++m) {
        const float* p = xp[m] + t * 64 + ks * 32;
        xr[ks][m][0] = *(const f32x4*)p;
        xr[ks][m][1] = *(const f32x4*)(p + 4);
      }
    // (3) write W(t+1) -> buf[cur^1]  (compiler waits counted vmcnt: the
    //     W(t+2)+X loads above are still outstanding)
    if (t + 1 < NK)
      *(bf16x8*)&Wl[cur ^ 1][half][wldst] = cvt8(rw[(t + 1) & 1][0], rw[(t + 1) & 1][1]);

    // (4) convert X fragments
    bf16x8 xa[2][2];
#pragma unroll
    for (int ks = 0; ks < 2; ++ks)
#pragma unroll
      for (int m = 0; m < 2; ++m)
        xa[ks][m] = cvt8(xr[ks][m][0], xr[ks][m][1]);

    // (5) B fragments from buf[cur] + MFMA
#pragma unroll
    for (int ks = 0; ks < 2; ++ks) {
      const int kg = ks * 4 + g4;
      bf16x8 bg[2], bu[2];
#pragma unroll
      for (int n = 0; n < 2; ++n) {
        const int brow = n * 16 + r16;
        const int u = brow * 64 + ((kg ^ (brow & 7)) << 3);
        bg[n] = *(bf16x8*)&Wl[cur][0][u];
        bu[n] = *(bf16x8*)&Wl[cur][1][u];
      }
#pragma unroll
      for (int n = 0; n < 2; ++n)
#pragma unroll
        for (int m = 0; m < 2; ++m) {
          ag[m][n] = __builtin_amdgcn_mfma_f32_16x16x32_bf16(xa[ks][m], bg[n], ag[m][n], 0, 0, 0);
          au[m][n] = __builtin_amdgcn_mfma_f32_16x16x32_bf16(xa[ks][m], bu[n], au[m][n], 0, 0, 0);
        }
    }

    __syncthreads();   // publish W(t+1) writes; protect next iter's write target
  }

  // epilogue: silu(gate)*up.  C/D map: col=lane&15, row=(lane>>4)*4+r
  const int c16 = lane & 15;
  const int r4  = (lane >> 4) * 4;
#pragma unroll
  for (int m = 0; m < 2; ++m)
#pragma unroll
    for (int n = 0; n < 2; ++n)
#pragma unroll
      for (int r = 0; r < 4; ++r) {
        float g = ag[m][n][r];
        float u = au[m][n][r];
        float a = (g / (1.f + __expf(-g))) * u;
        int b = m0 + m * 16 + r4 + r;
        int i = i0 + n * 16 + c16;
        act[((size_t)layer * BATCH + b) * INTER + i] = f2bf(a);
      }
}

// ---------------------------------------------------------------------------
// Kernel 2: out[b][layer][d] = act Wd^T.  UNCHANGED (R1 measured it at its
// ~roofline: ~68 us ~= (369 MB Wd + 46 MB act + 32 MB out)/6.3 TB/s).
// ---------------------------------------------------------------------------
#define BK 64

__device__ __forceinline__ void cvt_store8(ushort* dst, f32x4 a, f32x4 b) {
  *(bf16x8*)dst = cvt8(a, b);
}

__global__ __launch_bounds__(512) void k_down(
    const ushort* __restrict__ act, const float* __restrict__ Wd,
    float* __restrict__ out) {
  const int bid   = blockIdx.x;
  const int layer = bid / (HID / 64);
  const int dtile = bid % (HID / 64);
  const int d0    = dtile * 64;
  const int tid   = threadIdx.x;
  const int lane  = tid & 63;
  const int wave  = tid >> 6;
  const int wm    = wave >> 1;
  const int wn    = wave & 1;

  __shared__ ushort lds[BATCH * BK + 64 * BK];       // 40 KiB
  ushort* Al = lds;
  ushort* Wl = lds + BATCH * BK;

  f32x4 acc[4][2] = {};

  int aldst[4];
  const ushort* asrc[4];
#pragma unroll
  for (int r = 0; r < 4; ++r) {
    int g = tid + 512 * r;
    int arow = g >> 3, akc = g & 7;
    aldst[r] = arow * BK + ((akc ^ (arow & 7)) << 3);
    asrc[r] = act + ((size_t)layer * BATCH + arow) * INTER + akc * 8;
  }
  const int wrow = tid >> 3, wkc = tid & 7;
  const int wldst = wrow * BK + ((wkc ^ (wrow & 7)) << 3);
  const float* wsrc = Wd + (size_t)layer * HID * INTER + (size_t)(d0 + wrow) * INTER + wkc * 8;

  i32x4 ra[4];
  f32x4 rw[2];

#pragma unroll
  for (int r = 0; r < 4; ++r) ra[r] = *(const i32x4*)asrc[r];
  rw[0] = *(const f32x4*)wsrc; rw[1] = *(const f32x4*)(wsrc + 4);

  const int NK = INTER / BK;   // 44
  for (int k = 0; k < NK; ++k) {
    __syncthreads();
#pragma unroll
    for (int r = 0; r < 4; ++r) *(i32x4*)&Al[aldst[r]] = ra[r];
    cvt_store8(&Wl[wldst], rw[0], rw[1]);
    __syncthreads();

    if (k + 1 < NK) {
      int off = (k + 1) * BK;
#pragma unroll
      for (int r = 0; r < 4; ++r) ra[r] = *(const i32x4*)(asrc[r] + off);
      rw[0] = *(const f32x4*)(wsrc + off); rw[1] = *(const f32x4*)(wsrc + off + 4);
    }

#pragma unroll
    for (int ks = 0; ks < 2; ++ks) {
      const int kg = ks * 4 + (lane >> 4);
      bf16x8 af[4];
#pragma unroll
      for (int m = 0; m < 4; ++m) {
        int row = wm * 64 + m * 16 + (lane & 15);
        af[m] = *(bf16x8*)&Al[row * BK + ((kg ^ (row & 7)) << 3)];
      }
#pragma unroll
      for (int n = 0; n < 2; ++n) {
        int row = wn * 32 + n * 16 + (lane & 15);
        bf16x8 bw = *(bf16x8*)&Wl[row * BK + ((kg ^ (row & 7)) << 3)];
#pragma unroll
        for (int m = 0; m < 4; ++m)
          acc[m][n] = __builtin_amdgcn_mfma_f32_16x16x32_bf16(af[m], bw, acc[m][n], 0, 0, 0);
      }
    }
  }

  const int c16 = lane & 15;
  const int r4  = (lane >> 4) * 4;
#pragma unroll
  for (int m = 0; m < 4; ++m)
#pragma unroll
    for (int n = 0; n < 2; ++n)
#pragma unroll
      for (int r = 0; r < 4; ++r) {
        int b = wm * 64 + m * 16 + r4 + r;
        int d = d0 + wn * 32 + n * 16 + c16;
        out[(size_t)b * (NLAYERS * HID) + (size_t)layer * HID + d] = acc[m][n][r];
      }
}

extern "C" void kernel_launch(void* const* d_in, const int* in_sizes, int n_in,
                              void* d_out, int out_size, void* d_ws, size_t ws_size,
                              hipStream_t stream) {
  const float* h  = (const float*)d_in[0];
  const float* Wg = (const float*)d_in[1];
  const float* Wu = (const float*)d_in[2];
  const float* Wd = (const float*)d_in[3];
  float* out  = (float*)d_out;
  ushort* act = (ushort*)d_ws;   // 32*256*2816*2 = 46.1 MB of scratch

  hipLaunchKernelGGL(k_gateup, dim3(NLAYERS * (INTER / 32)), dim3(512), 0, stream,
                     h, Wg, Wu, act);
  hipLaunchKernelGGL(k_down, dim3(NLAYERS * (HID / 64)), dim3(512), 0, stream,
                     act, Wd, out);
}

// Round 4
// 328.960 us; speedup vs baseline: 1.5616x; 1.5616x over previous
//
#include <hip/hip_runtime.h>
#include <hip/hip_bf16.h>

#define BATCH   256
#define NLAYERS 32
#define HID     1024
#define INTER   2816
#define BK      64

typedef __attribute__((ext_vector_type(8))) short bf16x8;
typedef __attribute__((ext_vector_type(4))) float f32x4;
typedef __attribute__((ext_vector_type(4))) int   i32x4;

__device__ __forceinline__ ushort f2bf(float f) {
  __hip_bfloat16 b = __float2bfloat16(f);   // RNE
  return *reinterpret_cast<ushort*>(&b);
}

__device__ __forceinline__ bf16x8 cvt8(f32x4 a, f32x4 b) {
  bf16x8 o;
  o[0] = (short)f2bf(a[0]); o[1] = (short)f2bf(a[1]);
  o[2] = (short)f2bf(a[2]); o[3] = (short)f2bf(a[3]);
  o[4] = (short)f2bf(b[0]); o[5] = (short)f2bf(b[1]);
  o[6] = (short)f2bf(b[2]); o[7] = (short)f2bf(b[3]);
  return o;
}

// ---------------------------------------------------------------------------
// Kernel 0: pack h (B,N,D) fp32  ->  Xp[n][b][d] bf16 (layer-major, contiguous
// 2KB rows; one layer slice = 512 KB -> L2-resident for k_gateup).
// One wave per (b,n) row: 1024 floats = 4 f32x4/lane, coalesced in and out.
// ---------------------------------------------------------------------------
__global__ __launch_bounds__(256) void k_pack(
    const float* __restrict__ h, ushort* __restrict__ Xp) {
  const int r    = blockIdx.x * 4 + (threadIdx.x >> 6);   // 0..8191 = b*32+n
  const int lane = threadIdx.x & 63;
  const int ro   = ((r & 31) * 256 + (r >> 5)) * 1024;    // out row = n*256+b
  const float* src = h + (size_t)r * 1024 + lane * 4;
  ushort* dst      = Xp + ro + lane * 4;
#pragma unroll
  for (int g = 0; g < 4; ++g) {
    f32x4 v = *(const f32x4*)(src + g * 256);
    ushort4 o;
    o.x = f2bf(v[0]); o.y = f2bf(v[1]); o.z = f2bf(v[2]); o.w = f2bf(v[3]);
    *(ushort4*)(dst + g * 256) = o;
  }
}

// ---------------------------------------------------------------------------
// Kernel 1: act[layer][b][i] = silu(X Wg^T) * (X Wu^T), bf16 -> ws.
// EXACT k_down skeleton (measured ~6 TB/s): BM=256, 512 thr, BK=64, 40KB LDS,
// A staged as bf16 i32x4 copies, B staged fp32->bf16 (2 loads + 1 cvt8/thr),
// XOR swizzle (slot ^= row&7 on 16B slots of 128B rows; measured 0 conflicts),
// 2 barriers/step, register prefetch issued before the MFMA phase.
// B-tile = 64 rows: rows 0..31 = Wg[i0..i0+31], rows 32..63 = Wu[i0..i0+31].
// Waves 8M x 1N (wave owns 32 batch rows, all 64 B-rows) -> acc[m][0..1] =
// gate, acc[m][2..3] = up for the SAME output cols -> silu fusion is
// thread-local in the epilogue.
// ---------------------------------------------------------------------------
__global__ __launch_bounds__(512) void k_gateup(
    const ushort* __restrict__ Xp, const float* __restrict__ Wg,
    const float* __restrict__ Wu, ushort* __restrict__ act) {
  const int bid   = blockIdx.x;
  const int layer = bid / (INTER / 32);    // 88 itiles/layer
  const int it    = bid % (INTER / 32);
  const int i0    = it * 32;
  const int tid   = threadIdx.x;
  const int lane  = tid & 63;
  const int wave  = tid >> 6;
  const int m0    = wave * 32;             // wave-exclusive 32 batch rows

  __shared__ ushort lds[BATCH * BK + 64 * BK];   // 40 KiB
  ushort* Al = lds;
  ushort* Wl = lds + BATCH * BK;

  f32x4 acc[2][4] = {};                    // [m][n]; n 0..1 gate, 2..3 up

  // A staging: 2048 granules of 8 bf16; 4 per thread (i32x4 copy, no cvt)
  int aldst[4];
  const ushort* asrc[4];
#pragma unroll
  for (int r = 0; r < 4; ++r) {
    int g = tid + 512 * r;
    int arow = g >> 3, akc = g & 7;
    aldst[r] = arow * BK + ((akc ^ (arow & 7)) << 3);
    asrc[r] = Xp + ((size_t)layer * BATCH + arow) * HID + akc * 8;
  }
  // B staging: row t>>3 (0..63: <32 -> Wg, >=32 -> Wu), 8 floats at (t&7)*8
  const int wrow = tid >> 3, wsl = tid & 7;
  const int wldst = wrow * BK + ((wsl ^ (wrow & 7)) << 3);
  const float* wsrc = (wrow < 32 ? Wg + (size_t)(i0 + wrow) * HID
                                 : Wu + (size_t)(i0 + wrow - 32) * HID) +
                      (size_t)layer * INTER * HID + wsl * 8;

  i32x4 ra[4];
  f32x4 rw[2];
#pragma unroll
  for (int r = 0; r < 4; ++r) ra[r] = *(const i32x4*)asrc[r];
  rw[0] = *(const f32x4*)wsrc; rw[1] = *(const f32x4*)(wsrc + 4);

  const int r16 = lane & 15;
  const int g4  = lane >> 4;

  const int NK = HID / BK;                 // 16
  for (int k = 0; k < NK; ++k) {
    __syncthreads();
#pragma unroll
    for (int r = 0; r < 4; ++r) *(i32x4*)&Al[aldst[r]] = ra[r];
    *(bf16x8*)&Wl[wldst] = cvt8(rw[0], rw[1]);
    __syncthreads();

    if (k + 1 < NK) {                      // prefetch t+1 (in flight across MFMA)
      int off = (k + 1) * BK;
#pragma unroll
      for (int r = 0; r < 4; ++r) ra[r] = *(const i32x4*)(asrc[r] + off);
      rw[0] = *(const f32x4*)(wsrc + off); rw[1] = *(const f32x4*)(wsrc + off + 4);
    }

#pragma unroll
    for (int ks = 0; ks < 2; ++ks) {
      const int kg = ks * 4 + g4;
      bf16x8 af[2];
#pragma unroll
      for (int m = 0; m < 2; ++m) {
        int row = m0 + m * 16 + r16;
        af[m] = *(bf16x8*)&Al[row * BK + ((kg ^ (row & 7)) << 3)];
      }
#pragma unroll
      for (int n = 0; n < 4; ++n) {
        int row = n * 16 + r16;
        bf16x8 bw = *(bf16x8*)&Wl[row * BK + ((kg ^ (row & 7)) << 3)];
#pragma unroll
        for (int m = 0; m < 2; ++m)
          acc[m][n] = __builtin_amdgcn_mfma_f32_16x16x32_bf16(af[m], bw, acc[m][n], 0, 0, 0);
      }
    }
  }

  // epilogue: silu(gate)*up, thread-local.  C/D: col=lane&15, row=(lane>>4)*4+r
  const int r4 = (lane >> 4) * 4;
#pragma unroll
  for (int m = 0; m < 2; ++m)
#pragma unroll
    for (int n = 0; n < 2; ++n)
#pragma unroll
      for (int r = 0; r < 4; ++r) {
        float g = acc[m][n][r];
        float u = acc[m][n + 2][r];
        float a = (g / (1.f + __expf(-g))) * u;
        int b = m0 + m * 16 + r4 + r;
        int i = i0 + n * 16 + r16;
        act[((size_t)layer * BATCH + b) * INTER + i] = f2bf(a);
      }
}

// ---------------------------------------------------------------------------
// Kernel 2: out[b][layer][d] = act Wd^T.  UNCHANGED (measured ~65-68 us,
// ~its roofline: Wd 369 MB + act 46 MB (partly L3-hit) + out 32 MB write).
// ---------------------------------------------------------------------------
__global__ __launch_bounds__(512) void k_down(
    const ushort* __restrict__ act, const float* __restrict__ Wd,
    float* __restrict__ out) {
  const int bid   = blockIdx.x;
  const int layer = bid / (HID / 64);
  const int dtile = bid % (HID / 64);
  const int d0    = dtile * 64;
  const int tid   = threadIdx.x;
  const int lane  = tid & 63;
  const int wave  = tid >> 6;
  const int wm    = wave >> 1;
  const int wn    = wave & 1;

  __shared__ ushort lds[BATCH * BK + 64 * BK];       // 40 KiB
  ushort* Al = lds;
  ushort* Wl = lds + BATCH * BK;

  f32x4 acc[4][2] = {};

  int aldst[4];
  const ushort* asrc[4];
#pragma unroll
  for (int r = 0; r < 4; ++r) {
    int g = tid + 512 * r;
    int arow = g >> 3, akc = g & 7;
    aldst[r] = arow * BK + ((akc ^ (arow & 7)) << 3);
    asrc[r] = act + ((size_t)layer * BATCH + arow) * INTER + akc * 8;
  }
  const int wrow = tid >> 3, wkc = tid & 7;
  const int wldst = wrow * BK + ((wkc ^ (wrow & 7)) << 3);
  const float* wsrc = Wd + (size_t)layer * HID * INTER + (size_t)(d0 + wrow) * INTER + wkc * 8;

  i32x4 ra[4];
  f32x4 rw[2];

#pragma unroll
  for (int r = 0; r < 4; ++r) ra[r] = *(const i32x4*)asrc[r];
  rw[0] = *(const f32x4*)wsrc; rw[1] = *(const f32x4*)(wsrc + 4);

  const int NK = INTER / BK;   // 44
  for (int k = 0; k < NK; ++k) {
    __syncthreads();
#pragma unroll
    for (int r = 0; r < 4; ++r) *(i32x4*)&Al[aldst[r]] = ra[r];
    *(bf16x8*)&Wl[wldst] = cvt8(rw[0], rw[1]);
    __syncthreads();

    if (k + 1 < NK) {
      int off = (k + 1) * BK;
#pragma unroll
      for (int r = 0; r < 4; ++r) ra[r] = *(const i32x4*)(asrc[r] + off);
      rw[0] = *(const f32x4*)(wsrc + off); rw[1] = *(const f32x4*)(wsrc + off + 4);
    }

#pragma unroll
    for (int ks = 0; ks < 2; ++ks) {
      const int kg = ks * 4 + (lane >> 4);
      bf16x8 af[4];
#pragma unroll
      for (int m = 0; m < 4; ++m) {
        int row = wm * 64 + m * 16 + (lane & 15);
        af[m] = *(bf16x8*)&Al[row * BK + ((kg ^ (row & 7)) << 3)];
      }
#pragma unroll
      for (int n = 0; n < 2; ++n) {
        int row = wn * 32 + n * 16 + (lane & 15);
        bf16x8 bw = *(bf16x8*)&Wl[row * BK + ((kg ^ (row & 7)) << 3)];
#pragma unroll
        for (int m = 0; m < 4; ++m)
          acc[m][n] = __builtin_amdgcn_mfma_f32_16x16x32_bf16(af[m], bw, acc[m][n], 0, 0, 0);
      }
    }
  }

  const int c16 = lane & 15;
  const int r4  = (lane >> 4) * 4;
#pragma unroll
  for (int m = 0; m < 4; ++m)
#pragma unroll
    for (int n = 0; n < 2; ++n)
#pragma unroll
      for (int r = 0; r < 4; ++r) {
        int b = wm * 64 + m * 16 + r4 + r;
        int d = d0 + wn * 32 + n * 16 + c16;
        out[(size_t)b * (NLAYERS * HID) + (size_t)layer * HID + d] = acc[m][n][r];
      }
}

extern "C" void kernel_launch(void* const* d_in, const int* in_sizes, int n_in,
                              void* d_out, int out_size, void* d_ws, size_t ws_size,
                              hipStream_t stream) {
  const float* h  = (const float*)d_in[0];
  const float* Wg = (const float*)d_in[1];
  const float* Wu = (const float*)d_in[2];
  const float* Wd = (const float*)d_in[3];
  float* out  = (float*)d_out;
  ushort* act = (ushort*)d_ws;                                   // 46.1 MB
  ushort* Xp  = (ushort*)d_ws + (size_t)NLAYERS * BATCH * INTER; // +16.8 MB

  hipLaunchKernelGGL(k_pack, dim3(BATCH * NLAYERS / 4), dim3(256), 0, stream,
                     h, Xp);
  hipLaunchKernelGGL(k_gateup, dim3(NLAYERS * (INTER / 32)), dim3(512), 0, stream,
                     Xp, Wg, Wu, act);
  hipLaunchKernelGGL(k_down, dim3(NLAYERS * (HID / 64)), dim3(512), 0, stream,
                     act, Wd, out);
}